// Round 11
// baseline (200.296 us; speedup 1.0000x reference)
//
#include <hip/hip_runtime.h>

typedef _Float16 half8 __attribute__((ext_vector_type(8)));
typedef _Float16 half4_t __attribute__((ext_vector_type(4)));
typedef float f32x4 __attribute__((ext_vector_type(4)));

#define GK 1024
#define MEG (1024 * 1024)
#define LOG2E 1.44269504088896f

// async global->LDS, 16B per lane; lptr wave-uniform, lane i's data lands at lptr + i*16
#define GLD16(gptr, lptr) \
    __builtin_amdgcn_global_load_lds((const __attribute__((address_space(1))) void*)(gptr), \
                                     (__attribute__((address_space(3))) void*)(lptr), 16, 0, 0)

// ---------------- fp32 -> fp16 convert (all 5 tensors, one launch) ----------------
__global__ void cvt_all_kernel(const float* __restrict__ hidden,
                               const float* __restrict__ Wq,
                               const float* __restrict__ Wk,
                               const float* __restrict__ Wv,
                               const float* __restrict__ Wo,
                               _Float16* __restrict__ ws) {
    int b = blockIdx.x;
    const float* src;
    _Float16* dst;
    if (b < 4096)      { src = hidden; dst = ws; }
    else if (b < 5120) { src = Wq; dst = ws + 4 * MEG; b -= 4096; }
    else if (b < 6144) { src = Wk; dst = ws + 5 * MEG; b -= 5120; }
    else if (b < 7168) { src = Wv; dst = ws + 6 * MEG; b -= 6144; }
    else               { src = Wo; dst = ws + 7 * MEG; b -= 7168; }
    int i = (b * 256 + threadIdx.x) * 4;
    f32x4 v = *(const f32x4*)(src + i);
    half4_t h;
    h[0] = (_Float16)v[0]; h[1] = (_Float16)v[1];
    h[2] = (_Float16)v[2]; h[3] = (_Float16)v[3];
    *(half4_t*)(dst + i) = h;
}

// ---------------- QKV GEMM: C[4096,1024] = A @ B^T, z picks (Wq,Q)/(Wk,K)/(Wv,V) ----------------
// R10 decode: all 3 z's of one yb on one XCD -> per-XCD A set = 4 panels = 1MB
// (L2-resident, fetched once); A HBM traffic 24 -> 8 MB. z==2 writes VT directly.
__global__ __launch_bounds__(256) void gemm_qkv_kernel(
    const _Float16* __restrict__ A,
    const _Float16* __restrict__ B0,
    const _Float16* __restrict__ B1,
    const _Float16* __restrict__ B2,
    _Float16* __restrict__ O0,
    _Float16* __restrict__ O1,
    _Float16* __restrict__ O2)
{
    // lid = xcd + 8*(xb + 8*gidx); yb = xcd*4 + (gidx&3); z = gidx>>2  (bijective, 768)
    const int lid = blockIdx.x;
    const int xcd = lid & 7;
    const int rr = lid >> 3;              // 0..95
    const int xb = rr & 7;                // N-block
    const int gidx = rr >> 3;             // 0..11
    const int yb = xcd * 4 + (gidx & 3);  // 0..31
    const int z  = gidx >> 2;             // 0..2
    const _Float16* Bw = (z == 0) ? B0 : ((z == 1) ? B1 : B2);
    _Float16* Oh = (z == 0) ? O0 : ((z == 1) ? O1 : O2);

    __shared__ __attribute__((aligned(16))) _Float16 sA[2][128][32];
    __shared__ __attribute__((aligned(16))) _Float16 sB[2][128][32];

    const int tid = threadIdx.x;
    const int wave = tid >> 6, lane = tid & 63;
    const int quad = lane >> 4, l16 = lane & 15;
    const int wr = wave >> 1, wc = wave & 1;
    const int M0 = yb * 128, N0 = xb * 128;

    const int rl = lane >> 2;
    const int cl = (lane & 3) * 8;   // halfs within chunk
    const size_t aRow0 = (size_t)(M0 + wave * 16 + rl) * GK + cl;
    const size_t aRow1 = aRow0 + (size_t)64 * GK;
    const size_t bRow0 = (size_t)(N0 + wave * 16 + rl) * GK + cl;
    const size_t bRow1 = bRow0 + (size_t)64 * GK;
    _Float16* ldsA[2][2] = {{&sA[0][wave * 16][0], &sA[0][64 + wave * 16][0]},
                            {&sA[1][wave * 16][0], &sA[1][64 + wave * 16][0]}};
    _Float16* ldsB[2][2] = {{&sB[0][wave * 16][0], &sB[0][64 + wave * 16][0]},
                            {&sB[1][wave * 16][0], &sB[1][64 + wave * 16][0]}};

    f32x4 acc[4][4] = {};

    for (int kt = 0; kt < GK / 64; ++kt) {
        const int ko = kt * 64;
        #pragma unroll
        for (int c = 0; c < 2; ++c) {
            GLD16(A + aRow0 + ko + c * 32, ldsA[c][0]);
            GLD16(A + aRow1 + ko + c * 32, ldsA[c][1]);
            GLD16(Bw + bRow0 + ko + c * 32, ldsB[c][0]);
            GLD16(Bw + bRow1 + ko + c * 32, ldsB[c][1]);
        }
        __syncthreads();
        #pragma unroll
        for (int c = 0; c < 2; ++c) {
            half8 af[4], bf[4];
            #pragma unroll
            for (int i = 0; i < 4; ++i)
                af[i] = *(const half8*)&sA[c][wr * 64 + i * 16 + l16][quad * 8];
            #pragma unroll
            for (int j = 0; j < 4; ++j)
                bf[j] = *(const half8*)&sB[c][wc * 64 + j * 16 + l16][quad * 8];
            #pragma unroll
            for (int i = 0; i < 4; ++i)
                #pragma unroll
                for (int j = 0; j < 4; ++j)
                    acc[i][j] = __builtin_amdgcn_mfma_f32_16x16x32_f16(af[i], bf[j], acc[i][j], 0, 0, 0);
        }
        __syncthreads();
    }

    if (z == 2) {
        // V: store transposed [bh][d][s] (VT). Along r, s varies by 1 -> half4 store.
        #pragma unroll
        for (int i = 0; i < 4; ++i) {
            #pragma unroll
            for (int j = 0; j < 4; ++j) {
                int m = M0 + wr * 64 + i * 16 + quad * 4;        // r=0 base (s-dim)
                int n = N0 + wc * 64 + j * 16 + l16;
                int b = m >> 10, s = m & 1023, hh = n >> 6, d = n & 63;
                half4_t o;
                #pragma unroll
                for (int r = 0; r < 4; ++r) o[r] = (_Float16)acc[i][j][r];
                *(half4_t*)&Oh[((size_t)((b * 16 + hh) * 64 + d)) * 1024 + s] = o;
            }
        }
    } else {
        #pragma unroll
        for (int i = 0; i < 4; ++i) {
            #pragma unroll
            for (int j = 0; j < 4; ++j) {
                #pragma unroll
                for (int r = 0; r < 4; ++r) {
                    int m = M0 + wr * 64 + i * 16 + quad * 4 + r;
                    int n = N0 + wc * 64 + j * 16 + l16;
                    int b = m >> 10, s = m & 1023, hh = n >> 6, d = n & 63;
                    Oh[((size_t)((b * 16 + hh) * 1024 + s)) * 64 + d] = (_Float16)acc[i][j][r];
                }
            }
        }
    }
}

// ---------------- Output GEMM: C[4096,1024] fp32 = A @ B^T ----------------
__global__ __launch_bounds__(256) void gemm_o_kernel(
    const _Float16* __restrict__ A,
    const _Float16* __restrict__ Bw,
    float* __restrict__ Of)
{
    const int lid = blockIdx.x;
    const int xcd = lid & 7;
    const int rr = lid >> 3;              // 0..63
    const int xb = rr & 7;
    const int yb = xcd * 8 + (rr >> 3);   // 0..63

    __shared__ __attribute__((aligned(16))) _Float16 sA[2][64][32];
    __shared__ __attribute__((aligned(16))) _Float16 sB[2][128][32];

    const int tid = threadIdx.x;
    const int wave = tid >> 6, lane = tid & 63;
    const int quad = lane >> 4, l16 = lane & 15;
    const int M0 = yb * 64, N0 = xb * 128;

    const int rl = lane >> 2;
    const int cl = (lane & 3) * 8;
    const size_t aRow  = (size_t)(M0 + wave * 16 + rl) * GK + cl;
    const size_t bRow0 = (size_t)(N0 + wave * 16 + rl) * GK + cl;
    const size_t bRow1 = bRow0 + (size_t)64 * GK;
    _Float16* ldsA[2]    = {&sA[0][wave * 16][0], &sA[1][wave * 16][0]};
    _Float16* ldsB[2][2] = {{&sB[0][wave * 16][0], &sB[0][64 + wave * 16][0]},
                            {&sB[1][wave * 16][0], &sB[1][64 + wave * 16][0]}};

    f32x4 acc[4][2] = {};

    for (int kt = 0; kt < GK / 64; ++kt) {
        const int ko = kt * 64;
        #pragma unroll
        for (int c = 0; c < 2; ++c) {
            GLD16(A + aRow + ko + c * 32, ldsA[c]);
            GLD16(Bw + bRow0 + ko + c * 32, ldsB[c][0]);
            GLD16(Bw + bRow1 + ko + c * 32, ldsB[c][1]);
        }
        __syncthreads();
        #pragma unroll
        for (int c = 0; c < 2; ++c) {
            half8 af[4], bf[2];
            #pragma unroll
            for (int i = 0; i < 4; ++i)
                af[i] = *(const half8*)&sA[c][i * 16 + l16][quad * 8];
            #pragma unroll
            for (int j = 0; j < 2; ++j)
                bf[j] = *(const half8*)&sB[c][wave * 32 + j * 16 + l16][quad * 8];
            #pragma unroll
            for (int i = 0; i < 4; ++i)
                #pragma unroll
                for (int j = 0; j < 2; ++j)
                    acc[i][j] = __builtin_amdgcn_mfma_f32_16x16x32_f16(af[i], bf[j], acc[i][j], 0, 0, 0);
        }
        __syncthreads();
    }

    #pragma unroll
    for (int i = 0; i < 4; ++i) {
        #pragma unroll
        for (int j = 0; j < 2; ++j) {
            #pragma unroll
            for (int r = 0; r < 4; ++r) {
                int m = M0 + i * 16 + quad * 4 + r;
                int n = N0 + wave * 32 + j * 16 + l16;
                Of[(size_t)m * 1024 + n] = acc[i][j][r];
            }
        }
    }
}

// ---------------- flash attention, 8-wave QBLK=128, KVBLK=128 ----------------
// R10: KVBLK 64->128 on the proven R9 structure. Barriers per block 32->16; kf/pf/vf
// read totals IDENTICAL (PV in two 64-kpos half-passes reusing the 64-wide sP slice —
// wave-private, same-wave ds order guarantees write->read->overwrite correctness).
// LDS 73.25KB -> still 2 blocks/CU = 16 waves/CU (occupancy preserved, R6 lesson).
__global__ __launch_bounds__(512) void attn_kernel(
    const _Float16* __restrict__ Q,
    const _Float16* __restrict__ K,
    const _Float16* __restrict__ VT,
    const float* __restrict__ rel_bias,   // [32][16]
    _Float16* __restrict__ ctx)           // [B*S, 1024]
{
    const int S = 1024;
    const int qt = blockIdx.x;            // 0..7, QBLK=128
    const int q0 = qt * 128;
    const int h = blockIdx.y;
    const int b = blockIdx.z;
    const int bh = b * 16 + h;
    const _Float16* Qh = Q + (size_t)bh * S * 64;
    const _Float16* Kh = K + (size_t)bh * S * 64;
    const _Float16* VTh = VT + (size_t)bh * 64 * S;

    __shared__ __attribute__((aligned(16))) _Float16 sQ[128][72];
    __shared__ __attribute__((aligned(16))) _Float16 sK[128][72];    // [kpos][d]
    __shared__ __attribute__((aligned(16))) _Float16 sVt[64][136];   // [d][kpos 0..127]
    __shared__ __attribute__((aligned(16))) _Float16 sP[8][16][72];  // [wave][q=l16][kpos half]
    __shared__ _Float16 sBias[1152];

    const int tid = threadIdx.x;
    const int wave = tid >> 6, lane = tid & 63;
    const int quad = lane >> 4, l16 = lane & 15;

    {   // stage Q tile (once): 2 rows per thread
        int r = tid >> 3, c = (tid & 7) * 8;   // r 0..63
        *(half8*)&sQ[r][c]      = *(const half8*)(Qh + (size_t)(q0 + r) * 64 + c);
        *(half8*)&sQ[r + 64][c] = *(const half8*)(Qh + (size_t)(q0 + r + 64) * 64 + c);
    }
    // bias window: idx = kpos - q + q0 + 127 in [0,1150]
    for (int i = tid; i < 1151; i += 512) {
        int delta = i - (q0 + 127);            // kpos - q
        int rb = (delta > 0) ? 16 : 0;
        int n = (delta < 0) ? -delta : delta;
        int bucket;
        if (n < 8) bucket = rb + n;
        else bucket = rb + 8 + (n >= 12) + (n >= 16) + (n >= 23) + (n >= 32)
                             + (n >= 46) + (n >= 64) + (n >= 91);
        sBias[i] = (_Float16)rel_bias[bucket * 16 + h];
    }
    __syncthreads();

    // q-fragment: this wave's 16 q-rows (B-operand; lane l16 = q within group)
    half8 qf0 = *(const half8*)&sQ[wave * 16 + l16][quad * 8];
    half8 qf1 = *(const half8*)&sQ[wave * 16 + l16][32 + quad * 8];

    // K staging: 512 threads x 2 half8 cover 128x64; V: 2 half8 cover 64x128
    const int sr = tid >> 3;            // 0..63
    const int sc_ = (tid & 7) * 8;      // 0..56
    const _Float16* kp0 = Kh + (size_t)sr * 64 + sc_;          // += 8192 per kt
    const _Float16* kp1 = kp0 + (size_t)64 * 64;
    _Float16* sKw0 = &sK[sr][sc_];
    _Float16* sKw1 = &sK[sr + 64][sc_];
    const int vr = tid >> 4;            // 0..31
    const int vc = (tid & 15) * 8;      // 0..120
    const _Float16* vp0 = VTh + (size_t)vr * S + vc;           // += 128 per kt
    const _Float16* vp1 = vp0 + (size_t)32 * S;
    _Float16* sVw0 = &sVt[vr][vc];
    _Float16* sVw1 = &sVt[vr + 32][vc];

    // preload tile kt=0 into registers
    half8 rk0 = *(const half8*)kp0;
    half8 rk1 = *(const half8*)kp1;
    half8 rv0 = *(const half8*)vp0;
    half8 rv1 = *(const half8*)vp1;
    kp0 += 8192; kp1 += 8192; vp0 += 128; vp1 += 128;

    float m_run = -INFINITY, l_run = 0.0f;
    f32x4 acc[4] = {};   // acc[dt][r] = out^T[d = dt*16+quad*4+r][q = l16]

    for (int kt = 0; kt < 8; ++kt) {
        __syncthreads();   // prior iter's sK/sVt reads done
        *(half8*)sKw0 = rk0;
        *(half8*)sKw1 = rk1;
        *(half8*)sVw0 = rv0;
        *(half8*)sVw1 = rv1;
        __syncthreads();   // tile visible to all waves
        if (kt < 7) {      // prefetch next tile; latency hidden by compute below
            rk0 = *(const half8*)kp0;
            rk1 = *(const half8*)kp1;
            rv0 = *(const half8*)vp0;
            rv1 = *(const half8*)vp1;
            kp0 += 8192; kp1 += 8192; vp0 += 128; vp1 += 128;
        }

        // scores transposed: sc[j][r] = S[kpos = kt*128 + j*16 + quad*4 + r][q = l16]
        f32x4 sc[8] = {};
        #pragma unroll
        for (int j = 0; j < 8; ++j) {
            half8 kf0 = *(const half8*)&sK[j * 16 + l16][quad * 8];
            half8 kf1 = *(const half8*)&sK[j * 16 + l16][32 + quad * 8];
            sc[j] = __builtin_amdgcn_mfma_f32_16x16x32_f16(kf0, qf0, sc[j], 0, 0, 0);
            sc[j] = __builtin_amdgcn_mfma_f32_16x16x32_f16(kf1, qf1, sc[j], 0, 0, 0);
        }

        const int bbase = kt * 128 + quad * 4 - wave * 16 - l16 + 127;
        const bool uni = (kt <= qt - 2) || (kt >= qt + 2);   // 128-tile single-bucket
        float cb = 0.0f;
        if (uni) {
            cb = (float)sBias[bbase];
        } else {
            #pragma unroll
            for (int j = 0; j < 8; ++j)
                #pragma unroll
                for (int r = 0; r < 4; ++r)
                    sc[j][r] += (float)sBias[bbase + j * 16 + r];
        }
        // per-lane max over 32, then cross-quad reduce
        float t0 = fmaxf(fmaxf(sc[0][0], sc[0][1]), fmaxf(sc[0][2], sc[0][3]));
        float t1 = fmaxf(fmaxf(sc[1][0], sc[1][1]), fmaxf(sc[1][2], sc[1][3]));
        float t2 = fmaxf(fmaxf(sc[2][0], sc[2][1]), fmaxf(sc[2][2], sc[2][3]));
        float t3 = fmaxf(fmaxf(sc[3][0], sc[3][1]), fmaxf(sc[3][2], sc[3][3]));
        float t4 = fmaxf(fmaxf(sc[4][0], sc[4][1]), fmaxf(sc[4][2], sc[4][3]));
        float t5 = fmaxf(fmaxf(sc[5][0], sc[5][1]), fmaxf(sc[5][2], sc[5][3]));
        float t6 = fmaxf(fmaxf(sc[6][0], sc[6][1]), fmaxf(sc[6][2], sc[6][3]));
        float t7 = fmaxf(fmaxf(sc[7][0], sc[7][1]), fmaxf(sc[7][2], sc[7][3]));
        float mx = fmaxf(fmaxf(fmaxf(t0, t1), fmaxf(t2, t3)),
                         fmaxf(fmaxf(t4, t5), fmaxf(t6, t7)));
        mx = fmaxf(mx, __shfl_xor(mx, 16));
        mx = fmaxf(mx, __shfl_xor(mx, 32));
        float mnew = fmaxf(m_run, uni ? mx + cb : mx);
        float alpha = __expf(m_run - mnew);
        m_run = mnew;
        const float kk = ((uni ? cb : 0.0f) - mnew) * LOG2E;
        #pragma unroll
        for (int dt = 0; dt < 4; ++dt) acc[dt] *= alpha;   // rescale BEFORE PV
        float ps = 0.0f;

        // half A: kpos kt*128 + 0..63
        #pragma unroll
        for (int j = 0; j < 4; ++j) {
            half4_t pw;
            #pragma unroll
            for (int r = 0; r < 4; ++r) {
                float p = __builtin_exp2f(__builtin_fmaf(sc[j][r], LOG2E, kk));
                ps += p;
                pw[r] = (_Float16)p;
            }
            *(half4_t*)&sP[wave][l16][j * 16 + quad * 4] = pw;
        }
        {   // NO barrier: sP slice wave-private; same-wave ds order
            half8 pf0 = *(const half8*)&sP[wave][l16][quad * 8];
            half8 pf1 = *(const half8*)&sP[wave][l16][32 + quad * 8];
            #pragma unroll
            for (int dt = 0; dt < 4; ++dt) {
                half8 vf0 = *(const half8*)&sVt[dt * 16 + l16][quad * 8];
                half8 vf1 = *(const half8*)&sVt[dt * 16 + l16][32 + quad * 8];
                acc[dt] = __builtin_amdgcn_mfma_f32_16x16x32_f16(vf0, pf0, acc[dt], 0, 0, 0);
                acc[dt] = __builtin_amdgcn_mfma_f32_16x16x32_f16(vf1, pf1, acc[dt], 0, 0, 0);
            }
        }
        // half B: kpos kt*128 + 64..127 (sP slice reused after half-A PV consumed it)
        #pragma unroll
        for (int j = 4; j < 8; ++j) {
            half4_t pw;
            #pragma unroll
            for (int r = 0; r < 4; ++r) {
                float p = __builtin_exp2f(__builtin_fmaf(sc[j][r], LOG2E, kk));
                ps += p;
                pw[r] = (_Float16)p;
            }
            *(half4_t*)&sP[wave][l16][(j - 4) * 16 + quad * 4] = pw;
        }
        {
            half8 pf0 = *(const half8*)&sP[wave][l16][quad * 8];
            half8 pf1 = *(const half8*)&sP[wave][l16][32 + quad * 8];
            #pragma unroll
            for (int dt = 0; dt < 4; ++dt) {
                half8 vf0 = *(const half8*)&sVt[dt * 16 + l16][64 + quad * 8];
                half8 vf1 = *(const half8*)&sVt[dt * 16 + l16][96 + quad * 8];
                acc[dt] = __builtin_amdgcn_mfma_f32_16x16x32_f16(vf0, pf0, acc[dt], 0, 0, 0);
                acc[dt] = __builtin_amdgcn_mfma_f32_16x16x32_f16(vf1, pf1, acc[dt], 0, 0, 0);
            }
        }
        l_run = l_run * alpha + ps;
    }

    // final: reduce row-sum across quads, normalize, store half4 chunks
    l_run += __shfl_xor(l_run, 16);
    l_run += __shfl_xor(l_run, 32);
    const float inv = 1.0f / l_run;
    const size_t qg = (size_t)(b * 1024 + q0 + wave * 16 + l16);
    #pragma unroll
    for (int dt = 0; dt < 4; ++dt) {
        half4_t o;
        #pragma unroll
        for (int r = 0; r < 4; ++r) o[r] = (_Float16)(acc[dt][r] * inv);
        *(half4_t*)&ctx[qg * 1024 + h * 64 + dt * 16 + quad * 4] = o;
    }
}

// ---------------- launch ----------------
extern "C" void kernel_launch(void* const* d_in, const int* in_sizes, int n_in,
                              void* d_out, int out_size, void* d_ws, size_t ws_size,
                              hipStream_t stream) {
    const float* hidden   = (const float*)d_in[0];
    const float* Wq       = (const float*)d_in[1];
    const float* Wk       = (const float*)d_in[2];
    const float* Wv       = (const float*)d_in[3];
    const float* Wo       = (const float*)d_in[4];
    const float* rel_bias = (const float*)d_in[5];
    float* out = (float*)d_out;

    _Float16* ws    = (_Float16*)d_ws;
    _Float16* h16   = ws;                     // 4M halves (fp16 hidden)
    _Float16* wq16  = ws + 4 * (size_t)MEG;
    _Float16* wk16  = ws + 5 * (size_t)MEG;
    _Float16* wv16  = ws + 6 * (size_t)MEG;
    _Float16* wo16  = ws + 7 * (size_t)MEG;
    _Float16* Qs    = ws + 8 * (size_t)MEG;   // [B,H,S,64]
    _Float16* Ks    = ws + 12 * (size_t)MEG;
    _Float16* VTs   = ws + 16 * (size_t)MEG;  // V^T [B,H,64,S] — written by gemm_qkv z==2
    _Float16* ctx16 = ws + 20 * (size_t)MEG;  // [B*S,1024]

    cvt_all_kernel<<<8192, 256, 0, stream>>>(hidden, Wq, Wk, Wv, Wo, ws);

    // 1D grid, XCD-aware z-grouped decode (768 = 8 XCD x 12 x 8 N-blocks)
    gemm_qkv_kernel<<<dim3(768), 256, 0, stream>>>(
        h16, wq16, wk16, wv16, Qs, Ks, VTs);

    // 8-wave QBLK=128 KVBLK=128: 8 q-tiles x 16 heads x 4 batch = 512 blocks = 2/CU
    attn_kernel<<<dim3(8, 16, 4), 512, 0, stream>>>(Qs, Ks, VTs, rel_bias, ctx16);

    // 1D grid, XCD-aware decode (512 = 8 XCD x 8 groups x 8 N-blocks)
    gemm_o_kernel<<<dim3(512), 256, 0, stream>>>(ctx16, wo16, out);
}

// Round 15
// 186.811 us; speedup vs baseline: 1.0722x; 1.0722x over previous
//
#include <hip/hip_runtime.h>

typedef _Float16 half8 __attribute__((ext_vector_type(8)));
typedef _Float16 half4_t __attribute__((ext_vector_type(4)));
typedef float f32x4 __attribute__((ext_vector_type(4)));

#define GK 1024
#define MEG (1024 * 1024)
#define LOG2E 1.44269504088896f

// async global->LDS, 16B per lane; lptr wave-uniform, lane i's data lands at lptr + i*16
#define GLD16(gptr, lptr) \
    __builtin_amdgcn_global_load_lds((const __attribute__((address_space(1))) void*)(gptr), \
                                     (__attribute__((address_space(3))) void*)(lptr), 16, 0, 0)

// ---------------- fp32 -> fp16 convert (all 5 tensors, one launch) ----------------
__global__ void cvt_all_kernel(const float* __restrict__ hidden,
                               const float* __restrict__ Wq,
                               const float* __restrict__ Wk,
                               const float* __restrict__ Wv,
                               const float* __restrict__ Wo,
                               _Float16* __restrict__ ws) {
    int b = blockIdx.x;
    const float* src;
    _Float16* dst;
    if (b < 4096)      { src = hidden; dst = ws; }
    else if (b < 5120) { src = Wq; dst = ws + 4 * MEG; b -= 4096; }
    else if (b < 6144) { src = Wk; dst = ws + 5 * MEG; b -= 5120; }
    else if (b < 7168) { src = Wv; dst = ws + 6 * MEG; b -= 6144; }
    else               { src = Wo; dst = ws + 7 * MEG; b -= 7168; }
    int i = (b * 256 + threadIdx.x) * 4;
    f32x4 v = *(const f32x4*)(src + i);
    half4_t h;
    h[0] = (_Float16)v[0]; h[1] = (_Float16)v[1];
    h[2] = (_Float16)v[2]; h[3] = (_Float16)v[3];
    *(half4_t*)(dst + i) = h;
}

// ---------------- QKV GEMM: C[4096,1024] = A @ B^T, z picks (Wq,Q)/(Wk,K)/(Wv,V) ----------------
// XCD-aware 1D grid decode; z==2 (V) writes transposed [bh][d][s] directly.
__global__ __launch_bounds__(256) void gemm_qkv_kernel(
    const _Float16* __restrict__ A,
    const _Float16* __restrict__ B0,
    const _Float16* __restrict__ B1,
    const _Float16* __restrict__ B2,
    _Float16* __restrict__ O0,
    _Float16* __restrict__ O1,
    _Float16* __restrict__ O2)
{
    // decode: lid = xcd + 8*(xb + 8*gidx), gg = xcd*12 + gidx in [0,96), y=gg&31, z=gg>>5
    const int lid = blockIdx.x;
    const int xcd = lid & 7;
    const int rr = lid >> 3;              // 0..95
    const int xb = rr & 7;                // N-block
    const int gg = xcd * 12 + (rr >> 3);  // 0..95
    const int yb = gg & 31;               // M-block
    const int z  = gg >> 5;               // 0..2
    const _Float16* Bw = (z == 0) ? B0 : ((z == 1) ? B1 : B2);
    _Float16* Oh = (z == 0) ? O0 : ((z == 1) ? O1 : O2);

    __shared__ __attribute__((aligned(16))) _Float16 sA[2][128][32];
    __shared__ __attribute__((aligned(16))) _Float16 sB[2][128][32];

    const int tid = threadIdx.x;
    const int wave = tid >> 6, lane = tid & 63;
    const int quad = lane >> 4, l16 = lane & 15;
    const int wr = wave >> 1, wc = wave & 1;
    const int M0 = yb * 128, N0 = xb * 128;

    const int rl = lane >> 2;
    const int cl = (lane & 3) * 8;   // halfs within chunk
    const size_t aRow0 = (size_t)(M0 + wave * 16 + rl) * GK + cl;
    const size_t aRow1 = aRow0 + (size_t)64 * GK;
    const size_t bRow0 = (size_t)(N0 + wave * 16 + rl) * GK + cl;
    const size_t bRow1 = bRow0 + (size_t)64 * GK;
    _Float16* ldsA[2][2] = {{&sA[0][wave * 16][0], &sA[0][64 + wave * 16][0]},
                            {&sA[1][wave * 16][0], &sA[1][64 + wave * 16][0]}};
    _Float16* ldsB[2][2] = {{&sB[0][wave * 16][0], &sB[0][64 + wave * 16][0]},
                            {&sB[1][wave * 16][0], &sB[1][64 + wave * 16][0]}};

    f32x4 acc[4][4] = {};

    for (int kt = 0; kt < GK / 64; ++kt) {
        const int ko = kt * 64;
        #pragma unroll
        for (int c = 0; c < 2; ++c) {
            GLD16(A + aRow0 + ko + c * 32, ldsA[c][0]);
            GLD16(A + aRow1 + ko + c * 32, ldsA[c][1]);
            GLD16(Bw + bRow0 + ko + c * 32, ldsB[c][0]);
            GLD16(Bw + bRow1 + ko + c * 32, ldsB[c][1]);
        }
        __syncthreads();
        #pragma unroll
        for (int c = 0; c < 2; ++c) {
            half8 af[4], bf[4];
            #pragma unroll
            for (int i = 0; i < 4; ++i)
                af[i] = *(const half8*)&sA[c][wr * 64 + i * 16 + l16][quad * 8];
            #pragma unroll
            for (int j = 0; j < 4; ++j)
                bf[j] = *(const half8*)&sB[c][wc * 64 + j * 16 + l16][quad * 8];
            #pragma unroll
            for (int i = 0; i < 4; ++i)
                #pragma unroll
                for (int j = 0; j < 4; ++j)
                    acc[i][j] = __builtin_amdgcn_mfma_f32_16x16x32_f16(af[i], bf[j], acc[i][j], 0, 0, 0);
        }
        __syncthreads();
    }

    if (z == 2) {
        // V: store transposed [bh][d][s] (VT). Along r, s varies by 1 -> half4 store.
        #pragma unroll
        for (int i = 0; i < 4; ++i) {
            #pragma unroll
            for (int j = 0; j < 4; ++j) {
                int m = M0 + wr * 64 + i * 16 + quad * 4;        // r=0 base (s-dim)
                int n = N0 + wc * 64 + j * 16 + l16;
                int b = m >> 10, s = m & 1023, hh = n >> 6, d = n & 63;
                half4_t o;
                #pragma unroll
                for (int r = 0; r < 4; ++r) o[r] = (_Float16)acc[i][j][r];
                *(half4_t*)&Oh[((size_t)((b * 16 + hh) * 64 + d)) * 1024 + s] = o;
            }
        }
    } else {
        #pragma unroll
        for (int i = 0; i < 4; ++i) {
            #pragma unroll
            for (int j = 0; j < 4; ++j) {
                #pragma unroll
                for (int r = 0; r < 4; ++r) {
                    int m = M0 + wr * 64 + i * 16 + quad * 4 + r;
                    int n = N0 + wc * 64 + j * 16 + l16;
                    int b = m >> 10, s = m & 1023, hh = n >> 6, d = n & 63;
                    Oh[((size_t)((b * 16 + hh) * 1024 + s)) * 64 + d] = (_Float16)acc[i][j][r];
                }
            }
        }
    }
}

// ---------------- Output GEMM: C[4096,1024] fp32 = A @ B^T ----------------
__global__ __launch_bounds__(256) void gemm_o_kernel(
    const _Float16* __restrict__ A,
    const _Float16* __restrict__ Bw,
    float* __restrict__ Of)
{
    const int lid = blockIdx.x;
    const int xcd = lid & 7;
    const int rr = lid >> 3;              // 0..63
    const int xb = rr & 7;
    const int yb = xcd * 8 + (rr >> 3);   // 0..63

    __shared__ __attribute__((aligned(16))) _Float16 sA[2][64][32];
    __shared__ __attribute__((aligned(16))) _Float16 sB[2][128][32];

    const int tid = threadIdx.x;
    const int wave = tid >> 6, lane = tid & 63;
    const int quad = lane >> 4, l16 = lane & 15;
    const int M0 = yb * 64, N0 = xb * 128;

    const int rl = lane >> 2;
    const int cl = (lane & 3) * 8;
    const size_t aRow  = (size_t)(M0 + wave * 16 + rl) * GK + cl;
    const size_t bRow0 = (size_t)(N0 + wave * 16 + rl) * GK + cl;
    const size_t bRow1 = bRow0 + (size_t)64 * GK;
    _Float16* ldsA[2]    = {&sA[0][wave * 16][0], &sA[1][wave * 16][0]};
    _Float16* ldsB[2][2] = {{&sB[0][wave * 16][0], &sB[0][64 + wave * 16][0]},
                            {&sB[1][wave * 16][0], &sB[1][64 + wave * 16][0]}};

    f32x4 acc[4][2] = {};

    for (int kt = 0; kt < GK / 64; ++kt) {
        const int ko = kt * 64;
        #pragma unroll
        for (int c = 0; c < 2; ++c) {
            GLD16(A + aRow + ko + c * 32, ldsA[c]);
            GLD16(Bw + bRow0 + ko + c * 32, ldsB[c][0]);
            GLD16(Bw + bRow1 + ko + c * 32, ldsB[c][1]);
        }
        __syncthreads();
        #pragma unroll
        for (int c = 0; c < 2; ++c) {
            half8 af[4], bf[2];
            #pragma unroll
            for (int i = 0; i < 4; ++i)
                af[i] = *(const half8*)&sA[c][i * 16 + l16][quad * 8];
            #pragma unroll
            for (int j = 0; j < 2; ++j)
                bf[j] = *(const half8*)&sB[c][wave * 32 + j * 16 + l16][quad * 8];
            #pragma unroll
            for (int i = 0; i < 4; ++i)
                #pragma unroll
                for (int j = 0; j < 2; ++j)
                    acc[i][j] = __builtin_amdgcn_mfma_f32_16x16x32_f16(af[i], bf[j], acc[i][j], 0, 0, 0);
        }
        __syncthreads();
    }

    #pragma unroll
    for (int i = 0; i < 4; ++i) {
        #pragma unroll
        for (int j = 0; j < 2; ++j) {
            #pragma unroll
            for (int r = 0; r < 4; ++r) {
                int m = M0 + i * 16 + quad * 4 + r;
                int n = N0 + wave * 32 + j * 16 + l16;
                Of[(size_t)m * 1024 + n] = acc[i][j][r];
            }
        }
    }
}

// ---------------- flash attention, TRANSPOSED scores (K·Q^T), 8-wave QBLK=128 ----------------
// PROVEN BEST (R9: 53.3us, total 187.0us). Per-wave inner loop identical to the 4-wave
// baseline (16 q-rows/wave); 8 waves (512 thr) share one 128-row q-block. 2 blocks/CU
// x 8 waves = 16 waves/CU. Ledger of closed lines: setprio -, defer-max -, zero-staging
// --, XCD swizzle 0, 4-wave QBLK=128 - (occupancy), KVBLK=128 - (R11: LDS 75KB -> 1
// block/CU, occupancy cliff). Do not trade occupancy for per-unit-work reductions.
__global__ __launch_bounds__(512) void attn_kernel(
    const _Float16* __restrict__ Q,
    const _Float16* __restrict__ K,
    const _Float16* __restrict__ VT,
    const float* __restrict__ rel_bias,   // [32][16]
    _Float16* __restrict__ ctx)           // [B*S, 1024]
{
    const int S = 1024;
    const int qt = blockIdx.x;            // 0..7, QBLK=128
    const int q0 = qt * 128;
    const int h = blockIdx.y;
    const int b = blockIdx.z;
    const int bh = b * 16 + h;
    const _Float16* Qh = Q + (size_t)bh * S * 64;
    const _Float16* Kh = K + (size_t)bh * S * 64;
    const _Float16* VTh = VT + (size_t)bh * 64 * S;

    __shared__ __attribute__((aligned(16))) _Float16 sQ[128][72];
    __shared__ __attribute__((aligned(16))) _Float16 sK[64][72];
    __shared__ __attribute__((aligned(16))) _Float16 sVt[64][72];   // [d][kpos]
    __shared__ __attribute__((aligned(16))) _Float16 sP[8][16][72]; // [wave][q=l16][kpos]
    __shared__ _Float16 sBias[1152];

    const int tid = threadIdx.x;
    const int wave = tid >> 6, lane = tid & 63;
    const int quad = lane >> 4, l16 = lane & 15;

    {   // stage Q tile (once): 2 rows per thread
        int r = tid >> 3, c = (tid & 7) * 8;   // r 0..63
        *(half8*)&sQ[r][c]      = *(const half8*)(Qh + (size_t)(q0 + r) * 64 + c);
        *(half8*)&sQ[r + 64][c] = *(const half8*)(Qh + (size_t)(q0 + r + 64) * 64 + c);
    }
    // bias window: idx = kpos - q + q0 + 127 in [0,1150]
    for (int i = tid; i < 1151; i += 512) {
        int delta = i - (q0 + 127);            // kpos - q
        int rb = (delta > 0) ? 16 : 0;
        int n = (delta < 0) ? -delta : delta;
        int bucket;
        if (n < 8) bucket = rb + n;
        else bucket = rb + 8 + (n >= 12) + (n >= 16) + (n >= 23) + (n >= 32)
                             + (n >= 46) + (n >= 64) + (n >= 91);
        sBias[i] = (_Float16)rel_bias[bucket * 16 + h];
    }
    __syncthreads();

    // q-fragment: this wave's 16 q-rows (B-operand; lane l16 = q within group)
    half8 qf0 = *(const half8*)&sQ[wave * 16 + l16][quad * 8];
    half8 qf1 = *(const half8*)&sQ[wave * 16 + l16][32 + quad * 8];

    // staging: 512 threads cover the 64x64 K tile and V tile with ONE half8 each
    const int sr = tid >> 3;            // 0..63
    const int sc_ = (tid & 7) * 8;      // 0..56
    const _Float16* kp = Kh + (size_t)sr * 64 + sc_;           // += 4096 per kt
    const _Float16* vp = VTh + (size_t)sr * S + sc_;           // += 64 per kt
    _Float16* sKw = &sK[sr][sc_];
    _Float16* sVw = &sVt[sr][sc_];

    // preload tile kt=0 into registers
    half8 rk = *(const half8*)kp;
    half8 rv = *(const half8*)vp;
    kp += 4096; vp += 64;

    float m_run = -INFINITY, l_run = 0.0f;
    f32x4 acc[4] = {};   // acc[dt][r] = out^T[d = dt*16+quad*4+r][q = l16]

    for (int kt = 0; kt < 16; ++kt) {
        __syncthreads();   // prior iter's sK/sVt reads done
        *(half8*)sKw = rk;
        *(half8*)sVw = rv;
        __syncthreads();   // tile visible to all waves
        if (kt < 15) {     // prefetch next tile; latency hidden by compute below
            rk = *(const half8*)kp;
            rv = *(const half8*)vp;
            kp += 4096; vp += 64;
        }

        // scores transposed: sc[j][r] = S[kpos = kt*64 + j*16 + quad*4 + r][q = l16]
        f32x4 sc[4] = {};
        #pragma unroll
        for (int j = 0; j < 4; ++j) {
            half8 kf0 = *(const half8*)&sK[j * 16 + l16][quad * 8];
            half8 kf1 = *(const half8*)&sK[j * 16 + l16][32 + quad * 8];
            sc[j] = __builtin_amdgcn_mfma_f32_16x16x32_f16(kf0, qf0, sc[j], 0, 0, 0);
            sc[j] = __builtin_amdgcn_mfma_f32_16x16x32_f16(kf1, qf1, sc[j], 0, 0, 0);
        }

        const int bbase = kt * 64 + quad * 4 - wave * 16 - l16 + 127;
        float ps = 0.0f;
        if (kt <= 2 * qt - 3 || kt >= 2 * qt + 4) {
            // uniform tile: one bucket -> bias lane-uniform; fold bias & max into exp2 arg
            const float cb = (float)sBias[bbase];
            float mx = fmaxf(fmaxf(fmaxf(sc[0][0], sc[0][1]), fmaxf(sc[0][2], sc[0][3])),
                             fmaxf(fmaxf(sc[1][0], sc[1][1]), fmaxf(sc[1][2], sc[1][3])));
            mx = fmaxf(mx, fmaxf(fmaxf(fmaxf(sc[2][0], sc[2][1]), fmaxf(sc[2][2], sc[2][3])),
                                 fmaxf(fmaxf(sc[3][0], sc[3][1]), fmaxf(sc[3][2], sc[3][3]))));
            mx = fmaxf(mx, __shfl_xor(mx, 16));
            mx = fmaxf(mx, __shfl_xor(mx, 32));
            float mnew = fmaxf(m_run, mx + cb);
            float alpha = __expf(m_run - mnew);
            m_run = mnew;
            const float kk = (cb - mnew) * LOG2E;
            #pragma unroll
            for (int j = 0; j < 4; ++j) {
                half4_t pw;
                #pragma unroll
                for (int r = 0; r < 4; ++r) {
                    float p = __builtin_exp2f(__builtin_fmaf(sc[j][r], LOG2E, kk));
                    ps += p;
                    pw[r] = (_Float16)p;
                }
                *(half4_t*)&sP[wave][l16][j * 16 + quad * 4] = pw;
            }
            l_run = l_run * alpha + ps;
            #pragma unroll
            for (int dt = 0; dt < 4; ++dt) acc[dt] *= alpha;
        } else {
            // mixed tile: per-element bias (exact path)
            #pragma unroll
            for (int j = 0; j < 4; ++j)
                #pragma unroll
                for (int r = 0; r < 4; ++r)
                    sc[j][r] += (float)sBias[bbase + j * 16 + r];
            float mx = fmaxf(fmaxf(fmaxf(sc[0][0], sc[0][1]), fmaxf(sc[0][2], sc[0][3])),
                             fmaxf(fmaxf(sc[1][0], sc[1][1]), fmaxf(sc[1][2], sc[1][3])));
            mx = fmaxf(mx, fmaxf(fmaxf(fmaxf(sc[2][0], sc[2][1]), fmaxf(sc[2][2], sc[2][3])),
                                 fmaxf(fmaxf(sc[3][0], sc[3][1]), fmaxf(sc[3][2], sc[3][3]))));
            mx = fmaxf(mx, __shfl_xor(mx, 16));
            mx = fmaxf(mx, __shfl_xor(mx, 32));
            float mnew = fmaxf(m_run, mx);
            float alpha = __expf(m_run - mnew);
            m_run = mnew;
            #pragma unroll
            for (int j = 0; j < 4; ++j) {
                half4_t pw;
                #pragma unroll
                for (int r = 0; r < 4; ++r) {
                    float p = __expf(sc[j][r] - mnew);
                    ps += p;
                    pw[r] = (_Float16)p;
                }
                *(half4_t*)&sP[wave][l16][j * 16 + quad * 4] = pw;
            }
            l_run = l_run * alpha + ps;
            #pragma unroll
            for (int dt = 0; dt < 4; ++dt) acc[dt] *= alpha;
        }
        // NO barrier: sP slice is wave-private; same-wave ds_write -> ds_read is ordered.

        half8 pf0 = *(const half8*)&sP[wave][l16][quad * 8];        // B[n=q][k=kpos 0..31]
        half8 pf1 = *(const half8*)&sP[wave][l16][32 + quad * 8];   // kpos 32..63
        #pragma unroll
        for (int dt = 0; dt < 4; ++dt) {
            half8 vf0 = *(const half8*)&sVt[dt * 16 + l16][quad * 8];      // A[m=d][k=kpos]
            half8 vf1 = *(const half8*)&sVt[dt * 16 + l16][32 + quad * 8];
            acc[dt] = __builtin_amdgcn_mfma_f32_16x16x32_f16(vf0, pf0, acc[dt], 0, 0, 0);
            acc[dt] = __builtin_amdgcn_mfma_f32_16x16x32_f16(vf1, pf1, acc[dt], 0, 0, 0);
        }
    }

    // final: reduce row-sum across quads, normalize, store half4 chunks
    l_run += __shfl_xor(l_run, 16);
    l_run += __shfl_xor(l_run, 32);
    const float inv = 1.0f / l_run;
    const size_t qg = (size_t)(b * 1024 + q0 + wave * 16 + l16);
    #pragma unroll
    for (int dt = 0; dt < 4; ++dt) {
        half4_t o;
        #pragma unroll
        for (int r = 0; r < 4; ++r) o[r] = (_Float16)(acc[dt][r] * inv);
        *(half4_t*)&ctx[qg * 1024 + h * 64 + dt * 16 + quad * 4] = o;
    }
}

// ---------------- launch ----------------
extern "C" void kernel_launch(void* const* d_in, const int* in_sizes, int n_in,
                              void* d_out, int out_size, void* d_ws, size_t ws_size,
                              hipStream_t stream) {
    const float* hidden   = (const float*)d_in[0];
    const float* Wq       = (const float*)d_in[1];
    const float* Wk       = (const float*)d_in[2];
    const float* Wv       = (const float*)d_in[3];
    const float* Wo       = (const float*)d_in[4];
    const float* rel_bias = (const float*)d_in[5];
    float* out = (float*)d_out;

    _Float16* ws    = (_Float16*)d_ws;
    _Float16* h16   = ws;                     // 4M halves (fp16 hidden)
    _Float16* wq16  = ws + 4 * (size_t)MEG;
    _Float16* wk16  = ws + 5 * (size_t)MEG;
    _Float16* wv16  = ws + 6 * (size_t)MEG;
    _Float16* wo16  = ws + 7 * (size_t)MEG;
    _Float16* Qs    = ws + 8 * (size_t)MEG;   // [B,H,S,64]
    _Float16* Ks    = ws + 12 * (size_t)MEG;
    _Float16* VTs   = ws + 16 * (size_t)MEG;  // V^T [B,H,64,S] — written by gemm_qkv z==2
    _Float16* ctx16 = ws + 20 * (size_t)MEG;  // [B*S,1024]

    cvt_all_kernel<<<8192, 256, 0, stream>>>(hidden, Wq, Wk, Wv, Wo, ws);

    // 1D grid, XCD-aware decode (768 = 8 XCD x 12 groups x 8 N-blocks)
    gemm_qkv_kernel<<<dim3(768), 256, 0, stream>>>(
        h16, wq16, wk16, wv16, Qs, Ks, VTs);

    // 8-wave QBLK=128: 8 q-tiles x 16 heads x 4 batch = 512 blocks = 2/CU
    attn_kernel<<<dim3(8, 16, 4), 512, 0, stream>>>(Qs, Ks, VTs, rel_bias, ctx16);

    // 1D grid, XCD-aware decode (512 = 8 XCD x 8 groups x 8 N-blocks)
    gemm_o_kernel<<<dim3(512), 256, 0, stream>>>(ctx16, wo16, out);
}